// Round 1
// baseline (454.824 us; speedup 1.0000x reference)
//
#include <hip/hip_runtime.h>
#include <math.h>

// softmask: [B=16, K=64, H=240, W=320] fp32. Per-slice unbiased variance over
// H*W = 76800, sum the 1024 variances, sqrt -> scalar.
//
// Single fused kernel: one block per slice (256 threads, 75 float4/thread).
// Shift-by-0.5 keeps the S^2/n cancellation benign in fp32; per-slice variance
// is formed in double, atomically accumulated (f64 global atomic, device
// scope), and the last-arriving block (counter + threadfence release/acquire)
// does the sqrt. Workspace use: 16 bytes (double acc + uint counter), zeroed
// by a stream-ordered hipMemsetAsync (graph-capture safe).

#define HW_ELEMS     76800            // 240*320
#define F4_PER_SLICE (HW_ELEMS / 4)   // 19200
#define BLOCK        256
#define F4_PER_THR   (F4_PER_SLICE / BLOCK)  // 75 exactly
#define OUTER        5
#define INNER        (F4_PER_THR / OUTER)    // 15 — mirrors the verified chunk kernel's load batch

__global__ __launch_bounds__(BLOCK) void slice_var_kernel(
    const float* __restrict__ in, float* __restrict__ out,
    double* __restrict__ acc, unsigned int* __restrict__ cnt) {
    const long long slice = blockIdx.x;
    const float4* __restrict__ p =
        (const float4*)in + slice * F4_PER_SLICE + threadIdx.x;

    float s = 0.0f, q = 0.0f;
    for (int c = 0; c < OUTER; ++c) {
#pragma unroll
        for (int j = 0; j < INNER; ++j) {
            float4 v = p[(c * INNER + j) * BLOCK];
            float x = v.x - 0.5f, y = v.y - 0.5f, z = v.z - 0.5f, w = v.w - 0.5f;
            s += (x + y) + (z + w);
            q += x * x + y * y + z * z + w * w;
        }
    }

    // wave64 shuffle reduction
    for (int off = 32; off > 0; off >>= 1) {
        s += __shfl_down(s, off, 64);
        q += __shfl_down(q, off, 64);
    }

    __shared__ float ss[BLOCK / 64], qq[BLOCK / 64];
    if ((threadIdx.x & 63) == 0) {
        ss[threadIdx.x >> 6] = s;
        qq[threadIdx.x >> 6] = q;
    }
    __syncthreads();

    if (threadIdx.x == 0) {
        double S = 0.0, Q = 0.0;
        for (int w = 0; w < BLOCK / 64; ++w) { S += ss[w]; Q += qq[w]; }
        const double n = (double)HW_ELEMS;
        const double var = (Q - S * S / n) / (n - 1.0);

        atomicAdd(acc, var);          // device-scope f64 atomic (gfx90a+)
        __threadfence();              // release: acc add drained before counter bump
        const unsigned int old = atomicAdd(cnt, 1u);
        if (old == gridDim.x - 1) {   // last block to finish
            __threadfence();          // acquire
            const double tot = atomicAdd(acc, 0.0);  // coherent read of final sum
            out[0] = (float)sqrt(tot);
        }
    }
}

extern "C" void kernel_launch(void* const* d_in, const int* in_sizes, int n_in,
                              void* d_out, int out_size, void* d_ws, size_t ws_size,
                              hipStream_t stream) {
    const float* softmask = (const float*)d_in[0];
    float* out = (float*)d_out;
    double* acc = (double*)d_ws;                   // [0,8): accumulator
    unsigned int* cnt = (unsigned int*)((char*)d_ws + 8);  // [8,12): counter

    const int n_slices = in_sizes[0] / HW_ELEMS;   // 1024

    hipMemsetAsync(d_ws, 0, 16, stream);           // zero acc + counter (capturable)
    slice_var_kernel<<<n_slices, BLOCK, 0, stream>>>(softmask, out, acc, cnt);
}